// Round 4
// baseline (583.619 us; speedup 1.0000x reference)
//
#include <hip/hip_runtime.h>
#include <hip/hip_bf16.h>
#include <math.h>

#define D 128

typedef unsigned short ushort_t;
typedef __attribute__((ext_vector_type(8))) short bf16x8;
typedef __attribute__((ext_vector_type(4))) float f32x4;

// ---------- helpers ----------
__device__ __forceinline__ float bf2f(unsigned short u) {
    union { unsigned int i; float f; } c; c.i = ((unsigned int)u) << 16; return c.f;
}
__device__ __forceinline__ unsigned short f2bf(float f) {
    union { float f; unsigned int i; } c; c.f = f;
    unsigned int x = c.i + 0x7fffu + ((c.i >> 16) & 1u);   // RNE
    return (unsigned short)(x >> 16);
}
__device__ __forceinline__ float eluf(float x) { return x > 0.f ? x : (expf(x) - 1.f); }

// async global->LDS, 16B/lane; LDS dest = wave-uniform base + lane*16
__device__ __forceinline__ void gload_lds16(const void* g, void* l) {
    __builtin_amdgcn_global_load_lds(
        (const __attribute__((address_space(1))) unsigned int*)g,
        (__attribute__((address_space(3))) unsigned int*)l, 16, 0, 0);
}

// ---------- fused setup: [weight pack][x_item->bf16][bucket count] ----------
// Bpack per source: [kc(4)][nt(8)][lane(64)][j(8)]; element = W[k][n],
// k=kc*32+(lane>>4)*8+j, n=nt*16+(lane&15)
// slots: 0:A'=W1t-W1b 1:W1b 2:it_Wl 3:it_Wr 4:st_Wl 5:st_Wr 6:sc_W2
__global__ __launch_bounds__(256) void k_setup(
    const float* __restrict__ sc_W1, const float* __restrict__ it_Wl,
    const float* __restrict__ it_Wr, const float* __restrict__ st_Wl,
    const float* __restrict__ st_Wr, const float* __restrict__ sc_W2,
    ushort_t* __restrict__ Bpack,
    const float* __restrict__ x_item, ushort_t* __restrict__ xi16, int nxi,
    const int* __restrict__ rdst, const int* __restrict__ rsrc,
    const int* __restrict__ pdst, int* __restrict__ bucketCnt,
    int e_r, int e_p, int n_item, int n_stu, int PACKB, int CVTB) {
    __shared__ int cnt[256];
    int bx = blockIdx.x, tid = threadIdx.x;
    if (bx < PACKB) {
        int t = bx * 256 + tid;
        int s = t >> 14;
        int r = t & 16383;
        int j = r & 7;
        int lane = (r >> 3) & 63;
        int tile = r >> 9;
        int nt = tile & 7, kc = tile >> 3;
        int n = nt * 16 + (lane & 15);
        int k = kc * 32 + ((lane >> 4) << 3) + j;
        float v;
        switch (s) {
            case 0: v = sc_W1[k * 128 + n] - sc_W1[(128 + k) * 128 + n]; break;
            case 1: v = sc_W1[(128 + k) * 128 + n]; break;
            case 2: v = it_Wl[k * 128 + n]; break;
            case 3: v = it_Wr[k * 128 + n]; break;
            case 4: v = st_Wl[k * 128 + n]; break;
            case 5: v = st_Wr[k * 128 + n]; break;
            default: v = sc_W2[k * 128 + n]; break;
        }
        Bpack[t] = f2bf(v);
    } else if (bx < PACKB + CVTB) {
        int base = (bx - PACKB) * 2048 + tid * 8;
        if (base < nxi) {
            const float* g = x_item + base;
            float4 a0 = ((const float4*)g)[0];
            float4 a1 = ((const float4*)g)[1];
            ushort4 u0 = { f2bf(a0.x), f2bf(a0.y), f2bf(a0.z), f2bf(a0.w) };
            ushort4 u1 = { f2bf(a1.x), f2bf(a1.y), f2bf(a1.z), f2bf(a1.w) };
            *(ushort4*)(xi16 + base)     = u0;
            *(ushort4*)(xi16 + base + 4) = u1;
        }
    } else {
        int base = (bx - PACKB - CVTB) * 2048;
        int total = 2 * e_r + e_p;
        cnt[tid] = 0;
        __syncthreads();
        #pragma unroll
        for (int j = 0; j < 8; ++j) {
            int i = base + j * 256 + tid;
            if (i < total) {
                int g;
                if (i < e_r)            g = rdst[i];
                else if (i < 2 * e_r)   g = n_item + rsrc[i - e_r];
                else                    g = n_item + n_stu + pdst[i - 2 * e_r];
                atomicAdd(&cnt[g >> 10], 1);
            }
        }
        __syncthreads();
        if (cnt[tid] > 0) atomicAdd(&bucketCnt[tid], cnt[tid]);
    }
}

// ---------- bucket scan (1 block): bucketCnt -> bucketOff/bucketCursor ----------
__global__ __launch_bounds__(256) void k_bscan(const int* __restrict__ bucketCnt,
                                               int* __restrict__ bucketOff,
                                               int* __restrict__ bucketCursor,
                                               int NB, int tot_e,
                                               int* __restrict__ rowptr, int NN) {
    __shared__ int wsum[4];
    int tid = threadIdx.x, lane = tid & 63, w = tid >> 6;
    int v = (tid < NB) ? bucketCnt[tid] : 0;
    int orig = v;
    #pragma unroll
    for (int off = 1; off < 64; off <<= 1) {
        int t = __shfl_up(v, off, 64);
        if (lane >= off) v += t;
    }
    if (lane == 63) wsum[w] = v;
    __syncthreads();
    int wo = 0;
    #pragma unroll
    for (int i = 0; i < 4; ++i) if (i < w) wo += wsum[i];
    int excl = wo + v - orig;
    if (tid < NB) { bucketOff[tid] = excl; bucketCursor[tid] = excl; }
    if (tid == 0) { bucketOff[NB] = tot_e; rowptr[NN] = tot_e; }
}

// ---------- deposit: LDS-binned, coalesced-run append into bucket FIFOs ----------
// record (4B): (g & 1023) << 17 | src   (src < 131072, local_g < 1024)
__global__ __launch_bounds__(256) void k_deposit(const int* __restrict__ rdst,
                                                 const int* __restrict__ rsrc,
                                                 const int* __restrict__ pdst,
                                                 const int* __restrict__ psrc,
                                                 unsigned int* __restrict__ fifo,
                                                 int* __restrict__ bucketCursor,
                                                 int e_r, int e_p, int n_item, int n_stu) {
    __shared__ unsigned int recs[2048];
    __shared__ int cnt[256], excl[256], cur[256], scn[256];
    int tid = threadIdx.x;
    int base = blockIdx.x * 2048;
    int total = 2 * e_r + e_p;
    unsigned int myrec[8]; int myb[8];
    cnt[tid] = 0;
    __syncthreads();
    #pragma unroll
    for (int j = 0; j < 8; ++j) {
        int i = base + j * 256 + tid;
        if (i < total) {
            int g, s;
            if (i < e_r)          { g = rdst[i];                          s = rsrc[i]; }
            else if (i < 2 * e_r) { int q = i - e_r; g = n_item + rsrc[q]; s = rdst[q]; }
            else                  { int q = i - 2 * e_r; g = n_item + n_stu + pdst[q]; s = psrc[q]; }
            int b = g >> 10;
            myrec[j] = ((unsigned int)(g & 1023) << 17) | (unsigned int)s;
            myb[j] = b;
            atomicAdd(&cnt[b], 1);
        } else myb[j] = -1;
    }
    __syncthreads();
    scn[tid] = cnt[tid];
    __syncthreads();
    for (int s1 = 1; s1 < 256; s1 <<= 1) {
        int v = (tid >= s1) ? scn[tid - s1] : 0;
        __syncthreads();
        scn[tid] += v;
        __syncthreads();
    }
    excl[tid] = scn[tid] - cnt[tid];
    cur[tid] = excl[tid];
    __syncthreads();
    #pragma unroll
    for (int j = 0; j < 8; ++j) {
        if (myb[j] >= 0) {
            int p = atomicAdd(&cur[myb[j]], 1);
            recs[p] = myrec[j];
        }
    }
    __syncthreads();
    int wave = tid >> 6, lane = tid & 63;
    for (int b = wave; b < 256; b += 4) {
        int c = cnt[b];
        if (c == 0) continue;
        int gbase;
        if (lane == 0) gbase = atomicAdd(&bucketCursor[b], c);
        gbase = __shfl(gbase, 0);
        int lb = excl[b];
        for (int k = lane; k < c; k += 64) fifo[gbase + k] = recs[lb + k];
    }
}

// ---------- finalize: per-bucket node hist + scan -> rowptr; place payload ----------
__global__ __launch_bounds__(256) void k_finalize(const unsigned int* __restrict__ fifo,
                                                  const int* __restrict__ bucketOff,
                                                  int* __restrict__ rowptr,
                                                  int* __restrict__ payload,
                                                  int NN) {
    __shared__ int hist[1024];
    __shared__ int scn[256];
    __shared__ int cursor[1024];
    int b = blockIdx.x, tid = threadIdx.x;
    int nbase = b << 10;
    int f0 = bucketOff[b], f1 = bucketOff[b + 1];
    #pragma unroll
    for (int j = 0; j < 4; ++j) hist[tid * 4 + j] = 0;
    __syncthreads();
    for (int p = f0 + tid; p < f1; p += 256)
        atomicAdd(&hist[fifo[p] >> 17], 1);
    __syncthreads();
    int h0 = hist[tid * 4], h1 = hist[tid * 4 + 1], h2 = hist[tid * 4 + 2], h3 = hist[tid * 4 + 3];
    int tsum = h0 + h1 + h2 + h3;
    scn[tid] = tsum;
    __syncthreads();
    for (int s1 = 1; s1 < 256; s1 <<= 1) {
        int v = (tid >= s1) ? scn[tid - s1] : 0;
        __syncthreads();
        scn[tid] += v;
        __syncthreads();
    }
    int e0 = f0 + scn[tid] - tsum;
    int e1 = e0 + h0, e2 = e1 + h1, e3 = e2 + h2;
    cursor[tid * 4] = e0; cursor[tid * 4 + 1] = e1;
    cursor[tid * 4 + 2] = e2; cursor[tid * 4 + 3] = e3;
    int node = nbase + tid * 4;
    if (node + 3 < NN) {
        int4 rp = { e0, e1, e2, e3 };
        *(int4*)(rowptr + node) = rp;
    } else {
        if (node < NN)     rowptr[node]     = e0;
        if (node + 1 < NN) rowptr[node + 1] = e1;
        if (node + 2 < NN) rowptr[node + 2] = e2;
        if (node + 3 < NN) rowptr[node + 3] = e3;
    }
    __syncthreads();
    for (int p = f0 + tid; p < f1; p += 256) {
        unsigned int r = fifo[p];
        int pos = atomicAdd(&cursor[r >> 17], 1);
        payload[pos] = (int)(r & 0x1FFFFu);
    }
}

// ---------- aggregation: 32-lane half-wave per node, bf16 gathers, unroll-4 ----------
__global__ __launch_bounds__(256) void k_agg(const ushort_t* __restrict__ xs16,
                                             const ushort_t* __restrict__ xi16,
                                             const ushort_t* __restrict__ U,
                                             const ushort_t* __restrict__ V,
                                             const int* __restrict__ rowptr,
                                             const int* __restrict__ payload,
                                             float* __restrict__ agg_item,
                                             float* __restrict__ agg_stu,
                                             ushort_t* __restrict__ hm16,
                                             int n_item, int n_stu) {
    int t = blockIdx.x * 256 + threadIdx.x;
    int node = t >> 5;
    int lane = t & 31;
    int NN = n_item + 2 * n_stu;
    if (node >= NN) return;
    int p0 = rowptr[node], p1 = rowptr[node + 1];
    float inv = 1.0f / (float)max(p1 - p0, 1);
    float ax = 0.f, ay = 0.f, az = 0.f, aw = 0.f;
    if (node < n_item + n_stu) {
        const ushort_t* src = (node < n_item) ? xs16 : xi16;
        int p = p0;
        for (; p + 4 <= p1; p += 4) {
            int e0 = payload[p], e1 = payload[p + 1], e2 = payload[p + 2], e3 = payload[p + 3];
            ushort4 r0 = *(const ushort4*)(src + (size_t)e0 * D + lane * 4);
            ushort4 r1 = *(const ushort4*)(src + (size_t)e1 * D + lane * 4);
            ushort4 r2 = *(const ushort4*)(src + (size_t)e2 * D + lane * 4);
            ushort4 r3 = *(const ushort4*)(src + (size_t)e3 * D + lane * 4);
            ax += (bf2f(r0.x) + bf2f(r1.x)) + (bf2f(r2.x) + bf2f(r3.x));
            ay += (bf2f(r0.y) + bf2f(r1.y)) + (bf2f(r2.y) + bf2f(r3.y));
            az += (bf2f(r0.z) + bf2f(r1.z)) + (bf2f(r2.z) + bf2f(r3.z));
            aw += (bf2f(r0.w) + bf2f(r1.w)) + (bf2f(r2.w) + bf2f(r3.w));
        }
        for (; p < p1; ++p) {
            int e = payload[p];
            ushort4 r = *(const ushort4*)(src + (size_t)e * D + lane * 4);
            ax += bf2f(r.x); ay += bf2f(r.y); az += bf2f(r.z); aw += bf2f(r.w);
        }
        float4 o = { ax * inv, ay * inv, az * inv, aw * inv };
        if (node < n_item) *(float4*)(agg_item + (size_t)node * D + lane * 4) = o;
        else               *(float4*)(agg_stu + (size_t)(node - n_item) * D + lane * 4) = o;
    } else {
        int n = node - n_item - n_stu;
        ushort4 vu = *(const ushort4*)(V + (size_t)n * D + lane * 4);
        float vx = bf2f(vu.x), vy = bf2f(vu.y), vz = bf2f(vu.z), vw = bf2f(vu.w);
        int p = p0;
        for (; p + 4 <= p1; p += 4) {
            int e0 = payload[p], e1 = payload[p + 1], e2 = payload[p + 2], e3 = payload[p + 3];
            ushort4 r0 = *(const ushort4*)(U + (size_t)e0 * D + lane * 4);
            ushort4 r1 = *(const ushort4*)(U + (size_t)e1 * D + lane * 4);
            ushort4 r2 = *(const ushort4*)(U + (size_t)e2 * D + lane * 4);
            ushort4 r3 = *(const ushort4*)(U + (size_t)e3 * D + lane * 4);
            ax += (eluf(bf2f(r0.x) + vx) + eluf(bf2f(r1.x) + vx)) + (eluf(bf2f(r2.x) + vx) + eluf(bf2f(r3.x) + vx));
            ay += (eluf(bf2f(r0.y) + vy) + eluf(bf2f(r1.y) + vy)) + (eluf(bf2f(r2.y) + vy) + eluf(bf2f(r3.y) + vy));
            az += (eluf(bf2f(r0.z) + vz) + eluf(bf2f(r1.z) + vz)) + (eluf(bf2f(r2.z) + vz) + eluf(bf2f(r3.z) + vz));
            aw += (eluf(bf2f(r0.w) + vw) + eluf(bf2f(r1.w) + vw)) + (eluf(bf2f(r2.w) + vw) + eluf(bf2f(r3.w) + vw));
        }
        for (; p < p1; ++p) {
            int e = payload[p];
            ushort4 r = *(const ushort4*)(U + (size_t)e * D + lane * 4);
            ax += eluf(bf2f(r.x) + vx); ay += eluf(bf2f(r.y) + vy);
            az += eluf(bf2f(r.z) + vz); aw += eluf(bf2f(r.w) + vw);
        }
        ushort4 o = { f2bf(ax * inv), f2bf(ay * inv), f2bf(az * inv), f2bf(aw * inv) };
        *(ushort4*)(hm16 + (size_t)n * D + lane * 4) = o;
    }
}

// ---------- MFMA GEMM core: acc += sum_s A_s[M,128] @ Bpack_s ----------
__device__ __forceinline__ void gemm_core(const void* A0, int t0,
                                          const void* A1, int t1,
                                          const void* A2, int t2,
                                          int nsrc, const ushort_t* Bp0,
                                          int M, int row0, ushort_t* xside,
                                          short* As, short* Bs, f32x4 (&acc)[4][4]) {
    const int tid = threadIdx.x;
    const int wave = tid >> 6, lane = tid & 63;
    const int mh = wave >> 1, nh = wave & 1;
    const int q = lane >> 4, l15 = lane & 15;
    #pragma unroll
    for (int i = 0; i < 4; ++i)
        #pragma unroll
        for (int j = 0; j < 4; ++j) acc[i][j] = (f32x4){0.f, 0.f, 0.f, 0.f};

    for (int s = 0; s < nsrc; ++s) {
        const void* Ap = (s == 0) ? A0 : ((s == 1) ? A1 : A2);
        const int at = (s == 0) ? t0 : ((s == 1) ? t1 : t2);
        const ushort_t* Bp = Bp0 + s * 16384;
        for (int h = 0; h < 2; ++h) {
            __syncthreads();
            #pragma unroll
            for (int it = 0; it < 4; ++it) {
                int tile = wave * 4 + it;
                int mt = tile & 7, kc = tile >> 3;
                int row = row0 + mt * 16 + l15;
                if (row >= M) row = M - 1;
                int k = h * 64 + kc * 32 + (q << 3);
                if (at == 0) {
                    const float* g = (const float*)Ap + (size_t)row * D + k;
                    float4 a0 = ((const float4*)g)[0];
                    float4 a1 = ((const float4*)g)[1];
                    ushort4 u0 = { f2bf(a0.x), f2bf(a0.y), f2bf(a0.z), f2bf(a0.w) };
                    ushort4 u1 = { f2bf(a1.x), f2bf(a1.y), f2bf(a1.z), f2bf(a1.w) };
                    short* dst = &As[tile * 512 + lane * 8];
                    *(ushort4*)dst       = u0;
                    *(ushort4*)(dst + 4) = u1;
                    if (xside) {
                        ushort_t* o = xside + (size_t)row * D + k;
                        *(ushort4*)o       = u0;
                        *(ushort4*)(o + 4) = u1;
                    }
                } else {
                    gload_lds16((const ushort_t*)Ap + (size_t)row * D + k, &As[tile * 512]);
                }
            }
            const ushort_t* bsrc = Bp + h * 8192;
            #pragma unroll
            for (int it = 0; it < 4; ++it) {
                int tile = wave * 4 + it;
                gload_lds16(bsrc + tile * 512 + lane * 8, &Bs[tile * 512]);
            }
            __syncthreads();
            #pragma unroll
            for (int kc = 0; kc < 2; ++kc) {
                bf16x8 a[4], b[4];
                #pragma unroll
                for (int i = 0; i < 4; ++i)
                    a[i] = *(bf16x8*)&As[(kc * 8 + mh * 4 + i) * 512 + lane * 8];
                #pragma unroll
                for (int j = 0; j < 4; ++j)
                    b[j] = *(bf16x8*)&Bs[(kc * 8 + nh * 4 + j) * 512 + lane * 8];
                #pragma unroll
                for (int i = 0; i < 4; ++i)
                    #pragma unroll
                    for (int j = 0; j < 4; ++j)
                        acc[i][j] = __builtin_amdgcn_mfma_f32_16x16x32_bf16(a[i], b[j], acc[i][j], 0, 0, 0);
            }
        }
    }
}

// ---------- U/V GEMM: gridDim.y selects {U = xs@A'+b1} or {V = xs@W1b}; y=0 side-writes xs16 ----------
__global__ __launch_bounds__(256) void k_gemmUV(const float* __restrict__ xs,
                                                const ushort_t* __restrict__ Bpack,
                                                const float* __restrict__ b1,
                                                ushort_t* __restrict__ U,
                                                ushort_t* __restrict__ V,
                                                ushort_t* __restrict__ xs16, int M) {
    __shared__ short As[8192];
    __shared__ short Bs[8192];
    const int y = blockIdx.y;
    f32x4 acc[4][4];
    gemm_core(xs, 0, nullptr, 0, nullptr, 0, 1, Bpack + y * 16384, M,
              blockIdx.x * 128, y == 0 ? xs16 : nullptr, As, Bs, acc);
    const int tid = threadIdx.x;
    const int wave = tid >> 6, lane = tid & 63;
    const int mh = wave >> 1, nh = wave & 1;
    const int q = lane >> 4, l15 = lane & 15;
    ushort_t* C = (y == 0) ? U : V;
    float bv[4];
    #pragma unroll
    for (int j = 0; j < 4; ++j) {
        int col = (nh * 4 + j) * 16 + l15;
        bv[j] = (y == 0) ? b1[col] : 0.f;
    }
    const int row0 = blockIdx.x * 128;
    #pragma unroll
    for (int i = 0; i < 4; ++i) {
        int rowbase = row0 + (mh * 4 + i) * 16 + (q << 2);
        #pragma unroll
        for (int r = 0; r < 4; ++r) {
            int row = rowbase + r;
            if (row >= M) continue;
            #pragma unroll
            for (int j = 0; j < 4; ++j) {
                int col = (nh * 4 + j) * 16 + l15;
                C[(size_t)row * D + col] = f2bf(acc[i][j][r] + bv[j]);
            }
        }
    }
}

// ---------- final GEMM, fused item+stu by block range, ELU + BN-stats in epilogue ----------
__global__ __launch_bounds__(256) void k_gemmF(const float* __restrict__ agg_item,
                                               const ushort_t* __restrict__ xi16,
                                               const float* __restrict__ agg_stu,
                                               const ushort_t* __restrict__ xs16,
                                               const ushort_t* __restrict__ hm16,
                                               const ushort_t* __restrict__ Bpack,
                                               const float* __restrict__ it_b,
                                               const float* __restrict__ st_b,
                                               const float* __restrict__ sc_b2,
                                               const int* __restrict__ rowptrS,
                                               float* __restrict__ out_item,
                                               float* __restrict__ out_stu,
                                               float* __restrict__ stats,
                                               int n_item, int n_stu, int gs_item) {
    __shared__ short As[8192];
    __shared__ short Bs[8192];
    const int bx = blockIdx.x;
    const bool is_item = bx < gs_item;
    f32x4 acc[4][4];
    int M, row0;
    const float* bias;
    float scale;
    float* C;
    float* st;
    if (is_item) {
        M = n_item; row0 = bx * 128;
        gemm_core(agg_item, 0, xi16, 1, nullptr, 1, 2, Bpack + 2 * 16384, M, row0,
                  nullptr, As, Bs, acc);
        bias = it_b; scale = 1.f; C = out_item; st = stats;
    } else {
        M = n_stu; row0 = (bx - gs_item) * 128;
        gemm_core(agg_stu, 0, xs16, 1, hm16, 1, 3, Bpack + 4 * 16384, M, row0,
                  nullptr, As, Bs, acc);
        bias = st_b; scale = 0.5f; C = out_stu; st = stats + 256;
    }
    const int tid = threadIdx.x;
    const int wave = tid >> 6, lane = tid & 63;
    const int mh = wave >> 1, nh = wave & 1;
    const int q = lane >> 4, l15 = lane & 15;
    float* sred = (float*)As;   // reuse LDS for 256-float column reduction
    __syncthreads();            // all As/Bs reads done
    sred[tid] = 0.f;
    __syncthreads();
    float bv[4], b2v[4];
    #pragma unroll
    for (int j = 0; j < 4; ++j) {
        int col = (nh * 4 + j) * 16 + l15;
        bv[j]  = bias[col];
        b2v[j] = is_item ? 0.f : sc_b2[col];
    }
    float ps[4] = {0.f, 0.f, 0.f, 0.f}, pq[4] = {0.f, 0.f, 0.f, 0.f};
    #pragma unroll
    for (int i = 0; i < 4; ++i) {
        int rowbase = row0 + (mh * 4 + i) * 16 + (q << 2);
        #pragma unroll
        for (int r = 0; r < 4; ++r) {
            int row = rowbase + r;
            if (row >= M) continue;
            float g = 0.f;
            if (!is_item) g = (rowptrS[row + 1] - rowptrS[row]) > 0 ? 1.f : 0.f;
            #pragma unroll
            for (int j = 0; j < 4; ++j) {
                int col = (nh * 4 + j) * 16 + l15;
                float v = acc[i][j][r] + bv[j];
                if (!is_item) v += g * b2v[j];
                v *= scale;
                v = eluf(v);
                C[(size_t)row * D + col] = v;
                ps[j] += v; pq[j] += v * v;
            }
        }
    }
    #pragma unroll
    for (int j = 0; j < 4; ++j) {
        int col = (nh * 4 + j) * 16 + l15;
        atomicAdd(&sred[col], ps[j]);
        atomicAdd(&sred[128 + col], pq[j]);
    }
    __syncthreads();
    atomicAdd(&st[tid], sred[tid]);
}

// ---------- BN apply, fused item+stu, float4 ----------
__global__ __launch_bounds__(256) void k_bnapply(float* __restrict__ out_item,
                                                 float* __restrict__ out_stu,
                                                 const float* __restrict__ stats,
                                                 const float* __restrict__ g_i,
                                                 const float* __restrict__ b_i,
                                                 const float* __restrict__ g_s,
                                                 const float* __restrict__ b_s,
                                                 int n_item, int n_stu, int blkItem) {
    int bx = blockIdx.x;
    float* X; const float* st; const float* gamma; const float* beta;
    float invM; int idx;
    if (bx < blkItem) {
        X = out_item; st = stats; gamma = g_i; beta = b_i;
        invM = 1.f / (float)n_item; idx = bx * 1024 + threadIdx.x * 4;
    } else {
        X = out_stu; st = stats + 256; gamma = g_s; beta = b_s;
        invM = 1.f / (float)n_stu; idx = (bx - blkItem) * 1024 + threadIdx.x * 4;
    }
    int c = idx & 127;
    float4 x = *(float4*)(X + idx);
    float o[4];
    #pragma unroll
    for (int j = 0; j < 4; ++j) {
        float mu = st[c + j] * invM;
        float var = st[128 + c + j] * invM - mu * mu;
        float v = (j == 0) ? x.x : (j == 1) ? x.y : (j == 2) ? x.z : x.w;
        o[j] = gamma[c + j] * (v - mu) * rsqrtf(var + 1e-5f) + beta[c + j];
    }
    float4 ov = { o[0], o[1], o[2], o[3] };
    *(float4*)(X + idx) = ov;
}

// ---------- host ----------
extern "C" void kernel_launch(void* const* d_in, const int* in_sizes, int n_in,
                              void* d_out, int out_size, void* d_ws, size_t ws_size,
                              hipStream_t stream) {
    const float* x_stu   = (const float*)d_in[0];
    const float* x_item  = (const float*)d_in[1];
    const int*   rsrc    = (const int*)d_in[2];
    const int*   rdst    = (const int*)d_in[3];
    const int*   psrc    = (const int*)d_in[4];
    const int*   pdst    = (const int*)d_in[5];
    const float* it_Wl   = (const float*)d_in[6];
    const float* it_Wr   = (const float*)d_in[7];
    const float* it_b    = (const float*)d_in[8];
    const float* st_Wl   = (const float*)d_in[9];
    const float* st_Wr   = (const float*)d_in[10];
    const float* st_b    = (const float*)d_in[11];
    const float* sc_W1   = (const float*)d_in[12];
    const float* sc_b1   = (const float*)d_in[13];
    const float* sc_W2   = (const float*)d_in[14];
    const float* sc_b2   = (const float*)d_in[15];
    const float* bn_it_g = (const float*)d_in[16];
    const float* bn_it_b = (const float*)d_in[17];
    const float* bn_st_g = (const float*)d_in[18];
    const float* bn_st_b = (const float*)d_in[19];

    const int n_stu  = in_sizes[0] / D;
    const int n_item = in_sizes[1] / D;
    const int e_r    = in_sizes[2];
    const int e_p    = in_sizes[4];
    const int NN     = n_item + 2 * n_stu;
    const int tot_e  = 2 * e_r + e_p;
    const int NB     = (NN + 1023) / 1024;           // <= 256
    const int EB     = (tot_e + 2047) / 2048;

    // workspace layout (bucketCnt+stats adjacent for a single tiny memset)
    char* w = (char*)d_ws;
    size_t off = 0;
    auto alloc = [&](size_t bytes) { char* p = w + off; off = (off + bytes + 255) & ~(size_t)255; return p; };
    int*      bucketCnt    = (int*)alloc(256 * 4);
    float*    stats        = (float*)alloc(512 * 4);
    int*      bucketOff    = (int*)alloc(260 * 4);
    int*      bucketCursor = (int*)alloc(256 * 4);
    int*      rowptr       = (int*)alloc((size_t)(NN + 1) * 4);
    unsigned int* fifo     = (unsigned int*)alloc((size_t)tot_e * 4);
    int*      payload      = (int*)alloc((size_t)tot_e * 4);
    ushort_t* U      = (ushort_t*)alloc((size_t)n_stu * D * 2);
    ushort_t* V      = (ushort_t*)alloc((size_t)n_stu * D * 2);
    ushort_t* xs16   = (ushort_t*)alloc((size_t)n_stu * D * 2);
    ushort_t* xi16   = (ushort_t*)alloc((size_t)n_item * D * 2);
    ushort_t* hm16   = (ushort_t*)alloc((size_t)n_stu * D * 2);
    ushort_t* Bpack  = (ushort_t*)alloc(7 * 16384 * 2);
    (void)ws_size; (void)n_in; (void)out_size;

    // aggs staged fp32 in d_out (row-disjoint in-place for gemmF)
    float* out_item = (float*)d_out;
    float* out_stu  = (float*)d_out + (size_t)n_item * D;

    size_t zspan = (char*)(stats + 512) - (char*)bucketCnt;
    hipMemsetAsync(bucketCnt, 0, zspan, stream);

    const int PACKB = (7 * 16384) / 256;                 // 448
    const int nxi   = n_item * D;
    const int CVTB  = (nxi + 2047) / 2048;               // 1250
    k_setup<<<PACKB + CVTB + EB, 256, 0, stream>>>(
        sc_W1, it_Wl, it_Wr, st_Wl, st_Wr, sc_W2, Bpack,
        x_item, xi16, nxi, rdst, rsrc, pdst, bucketCnt,
        e_r, e_p, n_item, n_stu, PACKB, CVTB);

    k_bscan<<<1, 256, 0, stream>>>(bucketCnt, bucketOff, bucketCursor, NB, tot_e, rowptr, NN);
    k_deposit<<<EB, 256, 0, stream>>>(rdst, rsrc, pdst, psrc, fifo, bucketCursor,
                                      e_r, e_p, n_item, n_stu);
    k_finalize<<<NB, 256, 0, stream>>>(fifo, bucketOff, rowptr, payload, NN);

    const int gs_stu  = (n_stu + 127) / 128;
    const int gs_item = (n_item + 127) / 128;

    k_gemmUV<<<dim3(gs_stu, 2), 256, 0, stream>>>(x_stu, Bpack, sc_b1, U, V, xs16, n_stu);

    k_agg<<<((size_t)NN * 32 + 255) / 256, 256, 0, stream>>>(
        xs16, xi16, U, V, rowptr, payload, out_item, out_stu, hm16, n_item, n_stu);

    k_gemmF<<<gs_item + gs_stu, 256, 0, stream>>>(
        out_item, xi16, out_stu, xs16, hm16, Bpack, it_b, st_b, sc_b2,
        rowptr + n_item + n_stu, out_item, out_stu, stats, n_item, n_stu, gs_item);

    const int blkItem = (n_item * D) / 1024;             // 2500
    const int blkStu  = (n_stu * D) / 1024;              // 12500
    k_bnapply<<<blkItem + blkStu, 256, 0, stream>>>(
        out_item, out_stu, stats, bn_it_g, bn_it_b, bn_st_g, bn_st_b,
        n_item, n_stu, blkItem);
}

// Round 5
// 431.008 us; speedup vs baseline: 1.3541x; 1.3541x over previous
//
#include <hip/hip_runtime.h>
#include <hip/hip_bf16.h>
#include <math.h>

#define D 128

typedef unsigned short ushort_t;
typedef __attribute__((ext_vector_type(8))) short bf16x8;
typedef __attribute__((ext_vector_type(4))) float f32x4;

// ---------- helpers ----------
__device__ __forceinline__ float bf2f(unsigned short u) {
    union { unsigned int i; float f; } c; c.i = ((unsigned int)u) << 16; return c.f;
}
__device__ __forceinline__ unsigned short f2bf(float f) {
    union { float f; unsigned int i; } c; c.f = f;
    unsigned int x = c.i + 0x7fffu + ((c.i >> 16) & 1u);   // RNE
    return (unsigned short)(x >> 16);
}
__device__ __forceinline__ float eluf(float x) { return x > 0.f ? x : (expf(x) - 1.f); }

// async global->LDS, 16B/lane; LDS dest = wave-uniform base + lane*16
__device__ __forceinline__ void gload_lds16(const void* g, void* l) {
    __builtin_amdgcn_global_load_lds(
        (const __attribute__((address_space(1))) unsigned int*)g,
        (__attribute__((address_space(3))) unsigned int*)l, 16, 0, 0);
}

// ---------- fused setup: [weight pack][x_item->bf16][bucket count] ----------
__global__ __launch_bounds__(256) void k_setup(
    const float* __restrict__ sc_W1, const float* __restrict__ it_Wl,
    const float* __restrict__ it_Wr, const float* __restrict__ st_Wl,
    const float* __restrict__ st_Wr, const float* __restrict__ sc_W2,
    ushort_t* __restrict__ Bpack,
    const float* __restrict__ x_item, ushort_t* __restrict__ xi16, int nxi,
    const int* __restrict__ rdst, const int* __restrict__ rsrc,
    const int* __restrict__ pdst, int* __restrict__ bucketCnt,
    int e_r, int e_p, int n_item, int n_stu, int PACKB, int CVTB) {
    __shared__ int cnt[256];
    int bx = blockIdx.x, tid = threadIdx.x;
    if (bx < PACKB) {
        int t = bx * 256 + tid;
        int s = t >> 14;
        int r = t & 16383;
        int j = r & 7;
        int lane = (r >> 3) & 63;
        int tile = r >> 9;
        int nt = tile & 7, kc = tile >> 3;
        int n = nt * 16 + (lane & 15);
        int k = kc * 32 + ((lane >> 4) << 3) + j;
        float v;
        switch (s) {
            case 0: v = sc_W1[k * 128 + n] - sc_W1[(128 + k) * 128 + n]; break;
            case 1: v = sc_W1[(128 + k) * 128 + n]; break;
            case 2: v = it_Wl[k * 128 + n]; break;
            case 3: v = it_Wr[k * 128 + n]; break;
            case 4: v = st_Wl[k * 128 + n]; break;
            case 5: v = st_Wr[k * 128 + n]; break;
            default: v = sc_W2[k * 128 + n]; break;
        }
        Bpack[t] = f2bf(v);
    } else if (bx < PACKB + CVTB) {
        int base = (bx - PACKB) * 2048 + tid * 8;
        if (base < nxi) {
            const float* g = x_item + base;
            float4 a0 = ((const float4*)g)[0];
            float4 a1 = ((const float4*)g)[1];
            ushort4 u0 = { f2bf(a0.x), f2bf(a0.y), f2bf(a0.z), f2bf(a0.w) };
            ushort4 u1 = { f2bf(a1.x), f2bf(a1.y), f2bf(a1.z), f2bf(a1.w) };
            *(ushort4*)(xi16 + base)     = u0;
            *(ushort4*)(xi16 + base + 4) = u1;
        }
    } else {
        int base = (bx - PACKB - CVTB) * 2048;
        int total = 2 * e_r + e_p;
        cnt[tid] = 0;
        __syncthreads();
        #pragma unroll
        for (int j = 0; j < 8; ++j) {
            int i = base + j * 256 + tid;
            if (i < total) {
                int g;
                if (i < e_r)            g = rdst[i];
                else if (i < 2 * e_r)   g = n_item + rsrc[i - e_r];
                else                    g = n_item + n_stu + pdst[i - 2 * e_r];
                atomicAdd(&cnt[g >> 10], 1);
            }
        }
        __syncthreads();
        if (cnt[tid] > 0) atomicAdd(&bucketCnt[tid], cnt[tid]);
    }
}

// ---------- bucket scan (1 block): bucketCnt -> bucketOff/bucketCursor ----------
__global__ __launch_bounds__(256) void k_bscan(const int* __restrict__ bucketCnt,
                                               int* __restrict__ bucketOff,
                                               int* __restrict__ bucketCursor,
                                               int NB, int tot_e,
                                               int* __restrict__ rowptr, int NN) {
    __shared__ int wsum[4];
    int tid = threadIdx.x, lane = tid & 63, w = tid >> 6;
    int v = (tid < NB) ? bucketCnt[tid] : 0;
    int orig = v;
    #pragma unroll
    for (int off = 1; off < 64; off <<= 1) {
        int t = __shfl_up(v, off, 64);
        if (lane >= off) v += t;
    }
    if (lane == 63) wsum[w] = v;
    __syncthreads();
    int wo = 0;
    #pragma unroll
    for (int i = 0; i < 4; ++i) if (i < w) wo += wsum[i];
    int excl = wo + v - orig;
    if (tid < NB) { bucketOff[tid] = excl; bucketCursor[tid] = excl; }
    if (tid == 0) { bucketOff[NB] = tot_e; rowptr[NN] = tot_e; }
}

// ---------- deposit: LDS-binned; ALL bucket reservations issued in parallel ----------
// record (4B): (g & 1023) << 17 | src   (src < 131072, local_g < 1024)
__global__ __launch_bounds__(256) void k_deposit(const int* __restrict__ rdst,
                                                 const int* __restrict__ rsrc,
                                                 const int* __restrict__ pdst,
                                                 const int* __restrict__ psrc,
                                                 unsigned int* __restrict__ fifo,
                                                 int* __restrict__ bucketCursor,
                                                 int e_r, int e_p, int n_item, int n_stu) {
    __shared__ unsigned int recs[2048];
    __shared__ int cnt[256], excl[256], cur[256], scn[256], gb[256];
    int tid = threadIdx.x;
    int base = blockIdx.x * 2048;
    int total = 2 * e_r + e_p;
    unsigned int myrec[8]; int myb[8];
    cnt[tid] = 0;
    __syncthreads();
    #pragma unroll
    for (int j = 0; j < 8; ++j) {
        int i = base + j * 256 + tid;
        if (i < total) {
            int g, s;
            if (i < e_r)          { g = rdst[i];                          s = rsrc[i]; }
            else if (i < 2 * e_r) { int q = i - e_r; g = n_item + rsrc[q]; s = rdst[q]; }
            else                  { int q = i - 2 * e_r; g = n_item + n_stu + pdst[q]; s = psrc[q]; }
            int b = g >> 10;
            myrec[j] = ((unsigned int)(g & 1023) << 17) | (unsigned int)s;
            myb[j] = b;
            atomicAdd(&cnt[b], 1);
        } else myb[j] = -1;
    }
    __syncthreads();
    // one global reservation per thread(=bucket), all in flight simultaneously
    int myc = cnt[tid];
    if (myc > 0) gb[tid] = atomicAdd(&bucketCursor[tid], myc);
    scn[tid] = myc;
    __syncthreads();
    for (int s1 = 1; s1 < 256; s1 <<= 1) {
        int v = (tid >= s1) ? scn[tid - s1] : 0;
        __syncthreads();
        scn[tid] += v;
        __syncthreads();
    }
    excl[tid] = scn[tid] - cnt[tid];
    cur[tid] = excl[tid];
    __syncthreads();
    #pragma unroll
    for (int j = 0; j < 8; ++j) {
        if (myb[j] >= 0) {
            int p = atomicAdd(&cur[myb[j]], 1);
            recs[p] = myrec[j];
        }
    }
    __syncthreads();
    int wave = tid >> 6, lane = tid & 63;
    for (int b = wave; b < 256; b += 4) {
        int c = cnt[b];
        if (c == 0) continue;
        int gbase = gb[b];     // LDS read — no global round-trip in the loop
        int lb = excl[b];
        for (int k = lane; k < c; k += 64) fifo[gbase + k] = recs[lb + k];
    }
}

// ---------- finalize: per-bucket node hist + scan -> rowptr; place payload ----------
__global__ __launch_bounds__(256) void k_finalize(const unsigned int* __restrict__ fifo,
                                                  const int* __restrict__ bucketOff,
                                                  int* __restrict__ rowptr,
                                                  int* __restrict__ payload,
                                                  int NN) {
    __shared__ int hist[1024];
    __shared__ int scn[256];
    __shared__ int cursor[1024];
    int b = blockIdx.x, tid = threadIdx.x;
    int nbase = b << 10;
    int f0 = bucketOff[b], f1 = bucketOff[b + 1];
    #pragma unroll
    for (int j = 0; j < 4; ++j) hist[tid * 4 + j] = 0;
    __syncthreads();
    for (int p = f0 + tid; p < f1; p += 256)
        atomicAdd(&hist[fifo[p] >> 17], 1);
    __syncthreads();
    int h0 = hist[tid * 4], h1 = hist[tid * 4 + 1], h2 = hist[tid * 4 + 2], h3 = hist[tid * 4 + 3];
    int tsum = h0 + h1 + h2 + h3;
    scn[tid] = tsum;
    __syncthreads();
    for (int s1 = 1; s1 < 256; s1 <<= 1) {
        int v = (tid >= s1) ? scn[tid - s1] : 0;
        __syncthreads();
        scn[tid] += v;
        __syncthreads();
    }
    int e0 = f0 + scn[tid] - tsum;
    int e1 = e0 + h0, e2 = e1 + h1, e3 = e2 + h2;
    cursor[tid * 4] = e0; cursor[tid * 4 + 1] = e1;
    cursor[tid * 4 + 2] = e2; cursor[tid * 4 + 3] = e3;
    int node = nbase + tid * 4;
    if (node + 3 < NN) {
        int4 rp = { e0, e1, e2, e3 };
        *(int4*)(rowptr + node) = rp;
    } else {
        if (node < NN)     rowptr[node]     = e0;
        if (node + 1 < NN) rowptr[node + 1] = e1;
        if (node + 2 < NN) rowptr[node + 2] = e2;
        if (node + 3 < NN) rowptr[node + 3] = e3;
    }
    __syncthreads();
    for (int p = f0 + tid; p < f1; p += 256) {
        unsigned int r = fifo[p];
        int pos = atomicAdd(&cursor[r >> 17], 1);
        payload[pos] = (int)(r & 0x1FFFFu);
    }
}

// ---------- aggregation: 32-lane half-wave per node, bf16 gathers, unroll-4 ----------
__global__ __launch_bounds__(256) void k_agg(const ushort_t* __restrict__ xs16,
                                             const ushort_t* __restrict__ xi16,
                                             const ushort_t* __restrict__ U,
                                             const ushort_t* __restrict__ V,
                                             const int* __restrict__ rowptr,
                                             const int* __restrict__ payload,
                                             float* __restrict__ agg_item,
                                             float* __restrict__ agg_stu,
                                             ushort_t* __restrict__ hm16,
                                             int n_item, int n_stu) {
    int t = blockIdx.x * 256 + threadIdx.x;
    int node = t >> 5;
    int lane = t & 31;
    int NN = n_item + 2 * n_stu;
    if (node >= NN) return;
    int p0 = rowptr[node], p1 = rowptr[node + 1];
    float inv = 1.0f / (float)max(p1 - p0, 1);
    float ax = 0.f, ay = 0.f, az = 0.f, aw = 0.f;
    if (node < n_item + n_stu) {
        const ushort_t* src = (node < n_item) ? xs16 : xi16;
        int p = p0;
        for (; p + 4 <= p1; p += 4) {
            int e0 = payload[p], e1 = payload[p + 1], e2 = payload[p + 2], e3 = payload[p + 3];
            ushort4 r0 = *(const ushort4*)(src + (size_t)e0 * D + lane * 4);
            ushort4 r1 = *(const ushort4*)(src + (size_t)e1 * D + lane * 4);
            ushort4 r2 = *(const ushort4*)(src + (size_t)e2 * D + lane * 4);
            ushort4 r3 = *(const ushort4*)(src + (size_t)e3 * D + lane * 4);
            ax += (bf2f(r0.x) + bf2f(r1.x)) + (bf2f(r2.x) + bf2f(r3.x));
            ay += (bf2f(r0.y) + bf2f(r1.y)) + (bf2f(r2.y) + bf2f(r3.y));
            az += (bf2f(r0.z) + bf2f(r1.z)) + (bf2f(r2.z) + bf2f(r3.z));
            aw += (bf2f(r0.w) + bf2f(r1.w)) + (bf2f(r2.w) + bf2f(r3.w));
        }
        for (; p < p1; ++p) {
            int e = payload[p];
            ushort4 r = *(const ushort4*)(src + (size_t)e * D + lane * 4);
            ax += bf2f(r.x); ay += bf2f(r.y); az += bf2f(r.z); aw += bf2f(r.w);
        }
        float4 o = { ax * inv, ay * inv, az * inv, aw * inv };
        if (node < n_item) *(float4*)(agg_item + (size_t)node * D + lane * 4) = o;
        else               *(float4*)(agg_stu + (size_t)(node - n_item) * D + lane * 4) = o;
    } else {
        int n = node - n_item - n_stu;
        ushort4 vu = *(const ushort4*)(V + (size_t)n * D + lane * 4);
        float vx = bf2f(vu.x), vy = bf2f(vu.y), vz = bf2f(vu.z), vw = bf2f(vu.w);
        int p = p0;
        for (; p + 4 <= p1; p += 4) {
            int e0 = payload[p], e1 = payload[p + 1], e2 = payload[p + 2], e3 = payload[p + 3];
            ushort4 r0 = *(const ushort4*)(U + (size_t)e0 * D + lane * 4);
            ushort4 r1 = *(const ushort4*)(U + (size_t)e1 * D + lane * 4);
            ushort4 r2 = *(const ushort4*)(U + (size_t)e2 * D + lane * 4);
            ushort4 r3 = *(const ushort4*)(U + (size_t)e3 * D + lane * 4);
            ax += (eluf(bf2f(r0.x) + vx) + eluf(bf2f(r1.x) + vx)) + (eluf(bf2f(r2.x) + vx) + eluf(bf2f(r3.x) + vx));
            ay += (eluf(bf2f(r0.y) + vy) + eluf(bf2f(r1.y) + vy)) + (eluf(bf2f(r2.y) + vy) + eluf(bf2f(r3.y) + vy));
            az += (eluf(bf2f(r0.z) + vz) + eluf(bf2f(r1.z) + vz)) + (eluf(bf2f(r2.z) + vz) + eluf(bf2f(r3.z) + vz));
            aw += (eluf(bf2f(r0.w) + vw) + eluf(bf2f(r1.w) + vw)) + (eluf(bf2f(r2.w) + vw) + eluf(bf2f(r3.w) + vw));
        }
        for (; p < p1; ++p) {
            int e = payload[p];
            ushort4 r = *(const ushort4*)(U + (size_t)e * D + lane * 4);
            ax += eluf(bf2f(r.x) + vx); ay += eluf(bf2f(r.y) + vy);
            az += eluf(bf2f(r.z) + vz); aw += eluf(bf2f(r.w) + vw);
        }
        ushort4 o = { f2bf(ax * inv), f2bf(ay * inv), f2bf(az * inv), f2bf(aw * inv) };
        *(ushort4*)(hm16 + (size_t)n * D + lane * 4) = o;
    }
}

// ---------- MFMA GEMM core: acc += sum_s A_s[M,128] @ Bpack_s ----------
__device__ __forceinline__ void gemm_core(const void* A0, int t0,
                                          const void* A1, int t1,
                                          const void* A2, int t2,
                                          int nsrc, const ushort_t* Bp0,
                                          int M, int row0, ushort_t* xside,
                                          short* As, short* Bs, f32x4 (&acc)[4][4]) {
    const int tid = threadIdx.x;
    const int wave = tid >> 6, lane = tid & 63;
    const int mh = wave >> 1, nh = wave & 1;
    const int q = lane >> 4, l15 = lane & 15;
    #pragma unroll
    for (int i = 0; i < 4; ++i)
        #pragma unroll
        for (int j = 0; j < 4; ++j) acc[i][j] = (f32x4){0.f, 0.f, 0.f, 0.f};

    for (int s = 0; s < nsrc; ++s) {
        const void* Ap = (s == 0) ? A0 : ((s == 1) ? A1 : A2);
        const int at = (s == 0) ? t0 : ((s == 1) ? t1 : t2);
        const ushort_t* Bp = Bp0 + s * 16384;
        for (int h = 0; h < 2; ++h) {
            __syncthreads();
            #pragma unroll
            for (int it = 0; it < 4; ++it) {
                int tile = wave * 4 + it;
                int mt = tile & 7, kc = tile >> 3;
                int row = row0 + mt * 16 + l15;
                if (row >= M) row = M - 1;
                int k = h * 64 + kc * 32 + (q << 3);
                if (at == 0) {
                    const float* g = (const float*)Ap + (size_t)row * D + k;
                    float4 a0 = ((const float4*)g)[0];
                    float4 a1 = ((const float4*)g)[1];
                    ushort4 u0 = { f2bf(a0.x), f2bf(a0.y), f2bf(a0.z), f2bf(a0.w) };
                    ushort4 u1 = { f2bf(a1.x), f2bf(a1.y), f2bf(a1.z), f2bf(a1.w) };
                    short* dst = &As[tile * 512 + lane * 8];
                    *(ushort4*)dst       = u0;
                    *(ushort4*)(dst + 4) = u1;
                    if (xside) {
                        ushort_t* o = xside + (size_t)row * D + k;
                        *(ushort4*)o       = u0;
                        *(ushort4*)(o + 4) = u1;
                    }
                } else {
                    gload_lds16((const ushort_t*)Ap + (size_t)row * D + k, &As[tile * 512]);
                }
            }
            const ushort_t* bsrc = Bp + h * 8192;
            #pragma unroll
            for (int it = 0; it < 4; ++it) {
                int tile = wave * 4 + it;
                gload_lds16(bsrc + tile * 512 + lane * 8, &Bs[tile * 512]);
            }
            __syncthreads();
            #pragma unroll
            for (int kc = 0; kc < 2; ++kc) {
                bf16x8 a[4], b[4];
                #pragma unroll
                for (int i = 0; i < 4; ++i)
                    a[i] = *(bf16x8*)&As[(kc * 8 + mh * 4 + i) * 512 + lane * 8];
                #pragma unroll
                for (int j = 0; j < 4; ++j)
                    b[j] = *(bf16x8*)&Bs[(kc * 8 + nh * 4 + j) * 512 + lane * 8];
                #pragma unroll
                for (int i = 0; i < 4; ++i)
                    #pragma unroll
                    for (int j = 0; j < 4; ++j)
                        acc[i][j] = __builtin_amdgcn_mfma_f32_16x16x32_bf16(a[i], b[j], acc[i][j], 0, 0, 0);
            }
        }
    }
}

// ---------- U/V GEMM: gridDim.y selects {U = xs@A'+b1} or {V = xs@W1b}; y=0 side-writes xs16 ----------
__global__ __launch_bounds__(256) void k_gemmUV(const float* __restrict__ xs,
                                                const ushort_t* __restrict__ Bpack,
                                                const float* __restrict__ b1,
                                                ushort_t* __restrict__ U,
                                                ushort_t* __restrict__ V,
                                                ushort_t* __restrict__ xs16, int M) {
    __shared__ short As[8192];
    __shared__ short Bs[8192];
    const int y = blockIdx.y;
    f32x4 acc[4][4];
    gemm_core(xs, 0, nullptr, 0, nullptr, 0, 1, Bpack + y * 16384, M,
              blockIdx.x * 128, y == 0 ? xs16 : nullptr, As, Bs, acc);
    const int tid = threadIdx.x;
    const int wave = tid >> 6, lane = tid & 63;
    const int mh = wave >> 1, nh = wave & 1;
    const int q = lane >> 4, l15 = lane & 15;
    ushort_t* C = (y == 0) ? U : V;
    float bv[4];
    #pragma unroll
    for (int j = 0; j < 4; ++j) {
        int col = (nh * 4 + j) * 16 + l15;
        bv[j] = (y == 0) ? b1[col] : 0.f;
    }
    const int row0 = blockIdx.x * 128;
    #pragma unroll
    for (int i = 0; i < 4; ++i) {
        int rowbase = row0 + (mh * 4 + i) * 16 + (q << 2);
        #pragma unroll
        for (int r = 0; r < 4; ++r) {
            int row = rowbase + r;
            if (row >= M) continue;
            #pragma unroll
            for (int j = 0; j < 4; ++j) {
                int col = (nh * 4 + j) * 16 + l15;
                C[(size_t)row * D + col] = f2bf(acc[i][j][r] + bv[j]);
            }
        }
    }
}

// ---------- final GEMM, fused item+stu by block range, ELU + BN-stats in epilogue ----------
__global__ __launch_bounds__(256) void k_gemmF(const float* __restrict__ agg_item,
                                               const ushort_t* __restrict__ xi16,
                                               const float* __restrict__ agg_stu,
                                               const ushort_t* __restrict__ xs16,
                                               const ushort_t* __restrict__ hm16,
                                               const ushort_t* __restrict__ Bpack,
                                               const float* __restrict__ it_b,
                                               const float* __restrict__ st_b,
                                               const float* __restrict__ sc_b2,
                                               const int* __restrict__ rowptrS,
                                               float* __restrict__ out_item,
                                               float* __restrict__ out_stu,
                                               float* __restrict__ stats,
                                               int n_item, int n_stu, int gs_item) {
    __shared__ short As[8192];
    __shared__ short Bs[8192];
    const int bx = blockIdx.x;
    const bool is_item = bx < gs_item;
    f32x4 acc[4][4];
    int M, row0;
    const float* bias;
    float scale;
    float* C;
    float* st;
    if (is_item) {
        M = n_item; row0 = bx * 128;
        gemm_core(agg_item, 0, xi16, 1, nullptr, 1, 2, Bpack + 2 * 16384, M, row0,
                  nullptr, As, Bs, acc);
        bias = it_b; scale = 1.f; C = out_item; st = stats;
    } else {
        M = n_stu; row0 = (bx - gs_item) * 128;
        gemm_core(agg_stu, 0, xs16, 1, hm16, 1, 3, Bpack + 4 * 16384, M, row0,
                  nullptr, As, Bs, acc);
        bias = st_b; scale = 0.5f; C = out_stu; st = stats + 256;
    }
    const int tid = threadIdx.x;
    const int wave = tid >> 6, lane = tid & 63;
    const int mh = wave >> 1, nh = wave & 1;
    const int q = lane >> 4, l15 = lane & 15;
    float* sred = (float*)As;   // reuse LDS for 256-float column reduction
    __syncthreads();            // all As/Bs reads done
    sred[tid] = 0.f;
    __syncthreads();
    float bv[4], b2v[4];
    #pragma unroll
    for (int j = 0; j < 4; ++j) {
        int col = (nh * 4 + j) * 16 + l15;
        bv[j]  = bias[col];
        b2v[j] = is_item ? 0.f : sc_b2[col];
    }
    float ps[4] = {0.f, 0.f, 0.f, 0.f}, pq[4] = {0.f, 0.f, 0.f, 0.f};
    #pragma unroll
    for (int i = 0; i < 4; ++i) {
        int rowbase = row0 + (mh * 4 + i) * 16 + (q << 2);
        #pragma unroll
        for (int r = 0; r < 4; ++r) {
            int row = rowbase + r;
            if (row >= M) continue;
            float g = 0.f;
            if (!is_item) g = (rowptrS[row + 1] - rowptrS[row]) > 0 ? 1.f : 0.f;
            #pragma unroll
            for (int j = 0; j < 4; ++j) {
                int col = (nh * 4 + j) * 16 + l15;
                float v = acc[i][j][r] + bv[j];
                if (!is_item) v += g * b2v[j];
                v *= scale;
                v = eluf(v);
                C[(size_t)row * D + col] = v;
                ps[j] += v; pq[j] += v * v;
            }
        }
    }
    #pragma unroll
    for (int j = 0; j < 4; ++j) {
        int col = (nh * 4 + j) * 16 + l15;
        atomicAdd(&sred[col], ps[j]);
        atomicAdd(&sred[128 + col], pq[j]);
    }
    __syncthreads();
    atomicAdd(&st[tid], sred[tid]);
}

// ---------- BN apply, fused item+stu, float4 ----------
__global__ __launch_bounds__(256) void k_bnapply(float* __restrict__ out_item,
                                                 float* __restrict__ out_stu,
                                                 const float* __restrict__ stats,
                                                 const float* __restrict__ g_i,
                                                 const float* __restrict__ b_i,
                                                 const float* __restrict__ g_s,
                                                 const float* __restrict__ b_s,
                                                 int n_item, int n_stu, int blkItem) {
    int bx = blockIdx.x;
    float* X; const float* st; const float* gamma; const float* beta;
    float invM; int idx;
    if (bx < blkItem) {
        X = out_item; st = stats; gamma = g_i; beta = b_i;
        invM = 1.f / (float)n_item; idx = bx * 1024 + threadIdx.x * 4;
    } else {
        X = out_stu; st = stats + 256; gamma = g_s; beta = b_s;
        invM = 1.f / (float)n_stu; idx = (bx - blkItem) * 1024 + threadIdx.x * 4;
    }
    int c = idx & 127;
    float4 x = *(float4*)(X + idx);
    float o[4];
    #pragma unroll
    for (int j = 0; j < 4; ++j) {
        float mu = st[c + j] * invM;
        float var = st[128 + c + j] * invM - mu * mu;
        float v = (j == 0) ? x.x : (j == 1) ? x.y : (j == 2) ? x.z : x.w;
        o[j] = gamma[c + j] * (v - mu) * rsqrtf(var + 1e-5f) + beta[c + j];
    }
    float4 ov = { o[0], o[1], o[2], o[3] };
    *(float4*)(X + idx) = ov;
}

// ---------- host ----------
extern "C" void kernel_launch(void* const* d_in, const int* in_sizes, int n_in,
                              void* d_out, int out_size, void* d_ws, size_t ws_size,
                              hipStream_t stream) {
    const float* x_stu   = (const float*)d_in[0];
    const float* x_item  = (const float*)d_in[1];
    const int*   rsrc    = (const int*)d_in[2];
    const int*   rdst    = (const int*)d_in[3];
    const int*   psrc    = (const int*)d_in[4];
    const int*   pdst    = (const int*)d_in[5];
    const float* it_Wl   = (const float*)d_in[6];
    const float* it_Wr   = (const float*)d_in[7];
    const float* it_b    = (const float*)d_in[8];
    const float* st_Wl   = (const float*)d_in[9];
    const float* st_Wr   = (const float*)d_in[10];
    const float* st_b    = (const float*)d_in[11];
    const float* sc_W1   = (const float*)d_in[12];
    const float* sc_b1   = (const float*)d_in[13];
    const float* sc_W2   = (const float*)d_in[14];
    const float* sc_b2   = (const float*)d_in[15];
    const float* bn_it_g = (const float*)d_in[16];
    const float* bn_it_b = (const float*)d_in[17];
    const float* bn_st_g = (const float*)d_in[18];
    const float* bn_st_b = (const float*)d_in[19];

    const int n_stu  = in_sizes[0] / D;
    const int n_item = in_sizes[1] / D;
    const int e_r    = in_sizes[2];
    const int e_p    = in_sizes[4];
    const int NN     = n_item + 2 * n_stu;
    const int tot_e  = 2 * e_r + e_p;
    const int NB     = (NN + 1023) / 1024;           // <= 256
    const int EB     = (tot_e + 2047) / 2048;

    // workspace layout (bucketCnt+stats adjacent for a single tiny memset)
    char* w = (char*)d_ws;
    size_t off = 0;
    auto alloc = [&](size_t bytes) { char* p = w + off; off = (off + bytes + 255) & ~(size_t)255; return p; };
    int*      bucketCnt    = (int*)alloc(256 * 4);
    float*    stats        = (float*)alloc(512 * 4);
    int*      bucketOff    = (int*)alloc(260 * 4);
    int*      bucketCursor = (int*)alloc(256 * 4);
    int*      rowptr       = (int*)alloc((size_t)(NN + 1) * 4);
    unsigned int* fifo     = (unsigned int*)alloc((size_t)tot_e * 4);
    int*      payload      = (int*)alloc((size_t)tot_e * 4);
    ushort_t* U      = (ushort_t*)alloc((size_t)n_stu * D * 2);
    ushort_t* V      = (ushort_t*)alloc((size_t)n_stu * D * 2);
    ushort_t* xs16   = (ushort_t*)alloc((size_t)n_stu * D * 2);
    ushort_t* xi16   = (ushort_t*)alloc((size_t)n_item * D * 2);
    ushort_t* hm16   = (ushort_t*)alloc((size_t)n_stu * D * 2);
    ushort_t* Bpack  = (ushort_t*)alloc(7 * 16384 * 2);
    (void)ws_size; (void)n_in; (void)out_size;

    // aggs staged fp32 in d_out (row-disjoint in-place for gemmF)
    float* out_item = (float*)d_out;
    float* out_stu  = (float*)d_out + (size_t)n_item * D;

    size_t zspan = (char*)(stats + 512) - (char*)bucketCnt;
    hipMemsetAsync(bucketCnt, 0, zspan, stream);

    const int PACKB = (7 * 16384) / 256;                 // 448
    const int nxi   = n_item * D;
    const int CVTB  = (nxi + 2047) / 2048;               // 1250
    k_setup<<<PACKB + CVTB + EB, 256, 0, stream>>>(
        sc_W1, it_Wl, it_Wr, st_Wl, st_Wr, sc_W2, Bpack,
        x_item, xi16, nxi, rdst, rsrc, pdst, bucketCnt,
        e_r, e_p, n_item, n_stu, PACKB, CVTB);

    k_bscan<<<1, 256, 0, stream>>>(bucketCnt, bucketOff, bucketCursor, NB, tot_e, rowptr, NN);
    k_deposit<<<EB, 256, 0, stream>>>(rdst, rsrc, pdst, psrc, fifo, bucketCursor,
                                      e_r, e_p, n_item, n_stu);
    k_finalize<<<NB, 256, 0, stream>>>(fifo, bucketOff, rowptr, payload, NN);

    const int gs_stu  = (n_stu + 127) / 128;
    const int gs_item = (n_item + 127) / 128;

    k_gemmUV<<<dim3(gs_stu, 2), 256, 0, stream>>>(x_stu, Bpack, sc_b1, U, V, xs16, n_stu);

    k_agg<<<((size_t)NN * 32 + 255) / 256, 256, 0, stream>>>(
        xs16, xi16, U, V, rowptr, payload, out_item, out_stu, hm16, n_item, n_stu);

    k_gemmF<<<gs_item + gs_stu, 256, 0, stream>>>(
        out_item, xi16, out_stu, xs16, hm16, Bpack, it_b, st_b, sc_b2,
        rowptr + n_item + n_stu, out_item, out_stu, stats, n_item, n_stu, gs_item);

    const int blkItem = (n_item * D) / 1024;             // 2500
    const int blkStu  = (n_stu * D) / 1024;              // 12500
    k_bnapply<<<blkItem + blkStu, 256, 0, stream>>>(
        out_item, out_stu, stats, bn_it_g, bn_it_b, bn_st_g, bn_st_b,
        n_item, n_stu, blkItem);
}